// Round 2
// baseline (267.940 us; speedup 1.0000x reference)
//
#include <hip/hip_runtime.h>
#include <hip/hip_cooperative_groups.h>
#include <stdint.h>

namespace cg = cooperative_groups;

// Problem constants (fixed by the reference):
#define N_ROWS 262144
#define DIM    128
#define HID    16
#define NEXP   21
// Segments of 64 rows, each expert's region padded up to a multiple of 64.
#define NSEG   (N_ROWS / 64 + NEXP)   // 4096 + 21 = 4117 worst case
#define NBLK1  256                    // blocks for routing
#define RPB    (N_ROWS / NBLK1)       // 1024 rows per block
#define RPT    (RPB / 256)            // 4 rows per thread

// ---------------------------------------------------------------------------
// K_ROUTE (round 7): single cooperative kernel replacing
//   memset(buckets) + memset(counts) + k_hist + k_scatter   (4 dispatches -> 1).
//
// Rationale: r6's MFMA rewrite of k_main changed total dur by 0.1 us despite
// replacing a 4096-inst VALU loop with 48 MFMA -> k_main is HBM-floor-bound
// on the 134 MB x stream in BOTH versions (~25-30 us, below the 77-us poison
// fill so it never shows in top-5).  The controllable remainder is the
// routing preamble: 5 dispatches/iter where the real work is <10 us of
// traffic.  Collapse it:
//   Phase A: per-block histogram; each thread keeps its 4 rows' expert ids
//            in REGISTERS (sid read once, not twice).
//   grid.sync()  (256 blocks = 1/CU; cooperative launch guarantees residency)
//   Phase B: stage all 256x21 block-counts to LDS; each block derives expert
//            totals + its own prefix; scatters from registers.  Block 0
//            concurrently writes the -1 tail padding (pad slots are disjoint
//            from scattered slots -> no second sync).  Every bucket slot
//            k_mfma reads is written each iteration => no memsets needed.
// ---------------------------------------------------------------------------
__global__ __launch_bounds__(256) void k_route(const int* __restrict__ sid,
                                               int* __restrict__ blockCnt,
                                               int* __restrict__ buckets) {
    __shared__ int lh[NEXP];          // A: block hist;  B: expert totals
    __shared__ int wbase[NEXP];       // B: this block's write base per expert
    __shared__ int lcur[NEXP];
    __shared__ int ebase[NEXP + 1];   // padded expert bases; [NEXP]=paddedTotal
    __shared__ int cnt_s[NBLK1 * NEXP];   // 21504 B staging of all block hists

    const int t = threadIdx.x;
    const int b = blockIdx.x;
    if (t < NEXP) lh[t] = 0;
    __syncthreads();

    int er[RPT];
    const int rbase = b * RPB + t;
#pragma unroll
    for (int r = 0; r < RPT; r++) {
        er[r] = sid[rbase + r * 256];
        atomicAdd(&lh[er[r]], 1);
    }
    __syncthreads();
    if (t < NEXP) blockCnt[b * NEXP + t] = lh[t];

    __threadfence();                  // device-scope: cross-XCD visibility
    cg::this_grid().sync();

    // ---- Phase B ----
    for (int i = t; i < NBLK1 * NEXP; i += 256) cnt_s[i] = blockCnt[i];
    __syncthreads();

    if (t < NEXP) {
        int pre = 0, tot = 0;
#pragma unroll 8
        for (int bb = 0; bb < NBLK1; bb++) {
            int v = cnt_s[bb * NEXP + t];
            pre += (bb < b) ? v : 0;
            tot += v;
        }
        lh[t] = tot;
        wbase[t] = pre;               // prefix within expert (base added below)
        lcur[t] = 0;
    }
    __syncthreads();
    if (t == 0) {
        int acc = 0;
        for (int e = 0; e < NEXP; e++) {
            ebase[e] = acc;
            acc += ((lh[e] + 63) >> 6) << 6;   // pad each expert to 64
        }
        ebase[NEXP] = acc;            // paddedTotal  (<= NSEG*64)
    }
    __syncthreads();
    if (t < NEXP) wbase[t] += ebase[t];
    __syncthreads();

    // Scatter this block's rows (expert ids still in registers).
#pragma unroll
    for (int r = 0; r < RPT; r++) {
        const int e = er[r];
        const int lp = atomicAdd(&lcur[e], 1);
        buckets[wbase[e] + lp] = (rbase + r * 256) | (e << 24);
    }

    // Block 0: -1 padding (per-expert tails + region past paddedTotal).
    // Disjoint from all scattered slots, so no grid-wide ordering needed.
    if (b == 0) {
        for (int e = 0; e < NEXP; e++) {
            const int s = ebase[e] + lh[e];
            const int eend = ebase[e + 1];
            for (int i = s + t; i < eend; i += 256) buckets[i] = -1;
        }
        for (int i = ebase[NEXP] + t; i < NSEG * 64; i += 256) buckets[i] = -1;
    }
}

// ---------------------------------------------------------------------------
// Fallback routing kernels (used only if cooperative launch is unavailable).
// ---------------------------------------------------------------------------
__global__ __launch_bounds__(256) void k_hist(const int* __restrict__ sid,
                                              int* __restrict__ counts,
                                              int* __restrict__ blockBase) {
    __shared__ int lh[NEXP];
    int t = threadIdx.x;
    if (t < NEXP) lh[t] = 0;
    __syncthreads();
    int base = blockIdx.x * RPB + t;
#pragma unroll
    for (int r = 0; r < RPT; r++) {
        atomicAdd(&lh[sid[base + r * 256]], 1);
    }
    __syncthreads();
    if (t < NEXP) blockBase[blockIdx.x * NEXP + t] = atomicAdd(&counts[t], lh[t]);
}

__global__ __launch_bounds__(256) void k_scatter(const int* __restrict__ sid,
                                                 const int* __restrict__ counts,
                                                 const int* __restrict__ blockBase,
                                                 int* __restrict__ buckets) {
    __shared__ int sbase[NEXP];
    __shared__ int lcur[NEXP];
    int t = threadIdx.x;
    if (t == 0) {
        int acc = 0;
        for (int e = 0; e < NEXP; e++) {
            sbase[e] = acc + blockBase[blockIdx.x * NEXP + e];
            acc += ((counts[e] + 63) >> 6) << 6;
        }
    }
    if (t < NEXP) lcur[t] = 0;
    __syncthreads();
    int base = blockIdx.x * RPB + t;
#pragma unroll
    for (int r = 0; r < RPT; r++) {
        int row = base + r * 256;
        int e = sid[row];
        int lp = atomicAdd(&lcur[e], 1);
        buckets[sbase[e] + lp] = row | (e << 24);
    }
}

// ---------------------------------------------------------------------------
// K_MFMA (unchanged from round 6 — byte-identical; at the x-stream HBM floor).
// Split-bf16 (hi+lo, 3 products, fp32 accumulate): absmax 0.0078, passes.
// ---------------------------------------------------------------------------
typedef __attribute__((ext_vector_type(8))) short bf16x8;   // 8 bf16 = 4 VGPR
typedef __attribute__((ext_vector_type(4))) float f32x4;

__device__ __forceinline__ uint32_t pack2(uint32_t a, uint32_t b) {
    return __builtin_amdgcn_perm(b, a, 0x07060302u);  // bytes: b3 b2 a3 a2
}

__device__ __forceinline__ void cvt8(const float* f, bf16x8& fh, bf16x8& fl) {
    union { uint32_t u[4]; bf16x8 v; } H, L;
#pragma unroll
    for (int i = 0; i < 4; i++) {
        uint32_t a = __float_as_uint(f[2 * i]);
        uint32_t b = __float_as_uint(f[2 * i + 1]);
        H.u[i] = pack2(a, b);
        float ra = f[2 * i]     - __uint_as_float(a & 0xffff0000u);
        float rb = f[2 * i + 1] - __uint_as_float(b & 0xffff0000u);
        L.u[i] = pack2(__float_as_uint(ra), __float_as_uint(rb));
    }
    fh = H.v; fl = L.v;
}

__global__ __launch_bounds__(256, 4) void k_mfma(const float* __restrict__ x,
                                                 const float* __restrict__ W1,
                                                 const float* __restrict__ b1,
                                                 const float* __restrict__ W2,
                                                 const float* __restrict__ b2,
                                                 const int* __restrict__ buckets,
                                                 float* __restrict__ out) {
    const int seg = blockIdx.x * 4 + (threadIdx.x >> 6);
    if (seg >= NSEG) return;                       // wave-uniform
    const int lane = threadIdx.x & 63;

    const int ent = buckets[seg * 64 + lane];
    if (__ballot(ent >= 0) == 0ULL) return;        // wholly-empty tail segment
    const int e = __builtin_amdgcn_readfirstlane(ent) >> 24;
    const int row0 = __shfl(ent, 0, 64) & 0x00FFFFFF;
    const int vrow = (ent >= 0) ? (ent & 0x00FFFFFF) : row0;

    const int ncol  = lane & 15;        // A-row within tile / B,D column
    const int kbase = (lane >> 4) * 8;  // k offset within a K=32 step

    int arow[4];
#pragma unroll
    for (int mt = 0; mt < 4; mt++) arow[mt] = __shfl(vrow, mt * 16 + ncol, 64);

    const float* __restrict__ w1 = W1 + e * (DIM * HID);
    const float b1v = b1[e * HID + ncol];
    const float w2v = W2[e * HID + ncol];
    const float b2v = b2[e];

    const f32x4 zero = {0.0f, 0.0f, 0.0f, 0.0f};
    f32x4 acc[4] = {zero, zero, zero, zero};       // 4 M-tiles of 16 rows

#pragma unroll 1
    for (int kt = 0; kt < 4; kt++) {               // K = 128 = 4 steps of 32
        float bf[8];
        const float* wp = w1 + (kt * 32 + kbase) * HID + ncol;
#pragma unroll
        for (int t = 0; t < 8; t++) bf[t] = wp[t * HID];
        bf16x8 bh, bl;
        cvt8(bf, bh, bl);

#pragma unroll
        for (int mt = 0; mt < 4; mt++) {
            const float* xp = x + (size_t)arow[mt] * DIM + kt * 32 + kbase;
            float af[8];
            *(float4*)(af)     = *(const float4*)(xp);
            *(float4*)(af + 4) = *(const float4*)(xp + 4);
            bf16x8 ah, al;
            cvt8(af, ah, al);
            acc[mt] = __builtin_amdgcn_mfma_f32_16x16x32_bf16(ah, bh, acc[mt], 0, 0, 0);
            acc[mt] = __builtin_amdgcn_mfma_f32_16x16x32_bf16(al, bh, acc[mt], 0, 0, 0);
            acc[mt] = __builtin_amdgcn_mfma_f32_16x16x32_bf16(ah, bl, acc[mt], 0, 0, 0);
        }
    }

#pragma unroll
    for (int mt = 0; mt < 4; mt++) {
#pragma unroll
        for (int r = 0; r < 4; r++) {
            float c = fmaxf(acc[mt][r] + b1v, 0.0f) * w2v;
            c += __shfl_xor(c, 1, 64);
            c += __shfl_xor(c, 2, 64);
            c += __shfl_xor(c, 4, 64);
            c += __shfl_xor(c, 8, 64);
            const int slot = mt * 16 + (lane >> 4) * 4 + r;
            const int sent = __shfl(ent, slot, 64);
            if (ncol == 0 && sent >= 0)
                out[sent & 0x00FFFFFF] = fmaxf(c + b2v, 0.0f);
        }
    }
}

// ---------------------------------------------------------------------------
// Fallback (only if ws_size is too small for the buckets): thread-per-row.
// ---------------------------------------------------------------------------
__global__ __launch_bounds__(256) void k_naive(const float* __restrict__ x,
                                               const int* __restrict__ sid,
                                               const float* __restrict__ W1,
                                               const float* __restrict__ b1,
                                               const float* __restrict__ W2,
                                               const float* __restrict__ b2,
                                               float* __restrict__ out) {
    int row = blockIdx.x * 256 + threadIdx.x;
    if (row >= N_ROWS) return;
    int e = sid[row];
    const float* w1 = W1 + e * (DIM * HID);
    const float* xr = x + (size_t)row * DIM;
    float h[HID];
#pragma unroll
    for (int j = 0; j < HID; j++) h[j] = b1[e * HID + j];
    for (int k = 0; k < DIM; k++) {
        float xk = xr[k];
#pragma unroll
        for (int j = 0; j < HID; j++) h[j] = fmaf(xk, w1[k * HID + j], h[j]);
    }
    float acc = b2[e];
#pragma unroll
    for (int j = 0; j < HID; j++) acc = fmaf(fmaxf(h[j], 0.0f), W2[e * HID + j], acc);
    out[row] = fmaxf(acc, 0.0f);
}

extern "C" void kernel_launch(void* const* d_in, const int* in_sizes, int n_in,
                              void* d_out, int out_size, void* d_ws, size_t ws_size,
                              hipStream_t stream) {
    const float* x   = (const float*)d_in[0];
    const int*   sid = (const int*)d_in[1];
    const float* W1  = (const float*)d_in[2];
    const float* b1  = (const float*)d_in[3];
    const float* W2  = (const float*)d_in[4];
    const float* b2  = (const float*)d_in[5];
    float* out = (float*)d_out;

    // Workspace layout: buckets | blockCnt(NBLK1*NEXP) | counts(32)
    const size_t bucketBytes = (size_t)NSEG * 64 * sizeof(int);
    const size_t bcBytes     = (size_t)NBLK1 * NEXP * sizeof(int);
    const size_t countBytes  = 32 * sizeof(int);
    const size_t need = bucketBytes + bcBytes + countBytes;

    if (ws_size < need) {
        k_naive<<<(N_ROWS + 255) / 256, 256, 0, stream>>>(x, sid, W1, b1, W2, b2, out);
        return;
    }

    char* ws = (char*)d_ws;
    int* buckets  = (int*)ws;
    int* blockCnt = (int*)(ws + bucketBytes);
    int* counts   = (int*)(ws + bucketBytes + bcBytes);

    // Single cooperative routing dispatch (no memsets needed: k_route writes
    // every bucket slot each iteration).  Fallback to the classic path if
    // cooperative launch is unavailable under this runtime/capture mode.
    const int* sid_ = sid;
    int* bc_ = blockCnt;
    int* bk_ = buckets;
    void* args[] = {(void*)&sid_, (void*)&bc_, (void*)&bk_};
    hipError_t cerr = hipLaunchCooperativeKernel((const void*)k_route,
                                                 dim3(NBLK1), dim3(256),
                                                 args, 0, stream);
    if (cerr != hipSuccess) {
        hipMemsetAsync(buckets, 0xFF, bucketBytes, stream);   // all -1
        hipMemsetAsync(counts, 0, countBytes, stream);
        k_hist<<<NBLK1, 256, 0, stream>>>(sid, counts, blockCnt);
        k_scatter<<<NBLK1, 256, 0, stream>>>(sid, counts, blockCnt, buckets);
    }

    k_mfma<<<(NSEG + 3) / 4, 256, 0, stream>>>(x, W1, b1, W2, b2, buckets, out);
}

// Round 4
// 216.221 us; speedup vs baseline: 1.2392x; 1.2392x over previous
//
#include <hip/hip_runtime.h>
#include <stdint.h>

// Problem constants (fixed by the reference):
#define N_ROWS 262144
#define DIM    128
#define HID    16
#define NEXP   21
#define NSEG   (N_ROWS / 64 + NEXP)   // max total segments: 4096 + 21 = 4117
#define NBLK1  256                    // blocks for routing
#define RPB    (N_ROWS / NBLK1)       // 1024 rows per block
#define RPT    (RPB / 256)            // 4 rows per thread

// Fixed per-expert bucket regions: scatter needs no global prefix -> the
// hist+scatter fuse into ONE dispatch (no grid sync, no cooperative launch).
#define CAPSEG 4096                   // max segments one expert can need
#define REGION (CAPSEG * 64)          // ints per expert region (1 MB)

// ---------------------------------------------------------------------------
// ROUND 9 = byte-identical resubmission of round 8 (container infra failure,
// not a kernel signal: no compile error, no refcheck, no counters; source
// audit found no fault vector — all reads in-bounds, garbage lanes masked by
// lane<rem, no barriers after divergent exit, no cooperative launch).
//
// K_ROUTE: fused histogram + scatter, one dispatch.
// r7 post-mortem: cooperative launch REGRESSED +47 us (breaks graph capture /
// serializes the device).  Reverted.  The grid-wide dependency existed only
// because experts were packed contiguously (bases depend on final counts).
// With fixed per-expert regions a block needs only its own atomicAdd return
// on counts[e]:
//   - per-block LDS hist, expert ids held in registers (sid read ONCE)
//   - sbase[e] = atomicAdd(counts[e], lh[e])   (global base within region)
//   - scatter row ids to buckets[e*REGION + sbase[e] + lp]
// No -1 padding is written: k_mfma derives per-segment validity from counts
// (lane index < remainder), so unwritten poison slots are never interpreted.
// Dispatches/iter: 5 -> 3 (128-B memset + k_route + k_mfma).
// ---------------------------------------------------------------------------
__global__ __launch_bounds__(256) void k_route(const int* __restrict__ sid,
                                               int* __restrict__ counts,
                                               int* __restrict__ buckets) {
    __shared__ int lh[NEXP];
    __shared__ int sbase[NEXP];
    __shared__ int lcur[NEXP];
    const int t = threadIdx.x;
    if (t < NEXP) lh[t] = 0;
    __syncthreads();

    int er[RPT];
    const int rbase = blockIdx.x * RPB + t;
#pragma unroll
    for (int r = 0; r < RPT; r++) {
        er[r] = sid[rbase + r * 256];
        atomicAdd(&lh[er[r]], 1);
    }
    __syncthreads();
    if (t < NEXP) {
        sbase[t] = atomicAdd(&counts[t], lh[t]);   // global base in region
        lcur[t] = 0;
    }
    __syncthreads();
#pragma unroll
    for (int r = 0; r < RPT; r++) {
        const int e = er[r];
        const int lp = atomicAdd(&lcur[e], 1);
        buckets[e * REGION + sbase[e] + lp] = rbase + r * 256;
    }
}

// ---------------------------------------------------------------------------
// K_MFMA: unchanged math (split-bf16 hi+lo, 3 MFMA products, fp32 accumulate;
// at the 134-MB x-stream HBM floor).  Prologue maps the wave's linear segment
// id -> (expert, local segment, remainder) from the 21 final counts
// (wave-uniform scalar loop); entries are plain row indices and validity is
// lane<rem, so no sentinel reads.
// ---------------------------------------------------------------------------
typedef __attribute__((ext_vector_type(8))) short bf16x8;   // 8 bf16 = 4 VGPR
typedef __attribute__((ext_vector_type(4))) float f32x4;

__device__ __forceinline__ uint32_t pack2(uint32_t a, uint32_t b) {
    return __builtin_amdgcn_perm(b, a, 0x07060302u);  // bytes: b3 b2 a3 a2
}

__device__ __forceinline__ void cvt8(const float* f, bf16x8& fh, bf16x8& fl) {
    union { uint32_t u[4]; bf16x8 v; } H, L;
#pragma unroll
    for (int i = 0; i < 4; i++) {
        uint32_t a = __float_as_uint(f[2 * i]);
        uint32_t b = __float_as_uint(f[2 * i + 1]);
        H.u[i] = pack2(a, b);
        float ra = f[2 * i]     - __uint_as_float(a & 0xffff0000u);
        float rb = f[2 * i + 1] - __uint_as_float(b & 0xffff0000u);
        L.u[i] = pack2(__float_as_uint(ra), __float_as_uint(rb));
    }
    fh = H.v; fl = L.v;
}

__global__ __launch_bounds__(256, 4) void k_mfma(const float* __restrict__ x,
                                                 const float* __restrict__ W1,
                                                 const float* __restrict__ b1,
                                                 const float* __restrict__ W2,
                                                 const float* __restrict__ b2,
                                                 const int* __restrict__ counts,
                                                 const int* __restrict__ buckets,
                                                 float* __restrict__ out) {
    const int seg = blockIdx.x * 4 + (threadIdx.x >> 6);   // wave-uniform

    // Map seg -> (expert e, local segment ls, valid rows rem).
    int e = -1, ls = 0, rem = 0, cum = 0;
#pragma unroll
    for (int i = 0; i < NEXP; i++) {
        const int c = counts[i];                 // uniform -> scalar loads
        const int ns = (c + 63) >> 6;
        if (e < 0 && seg < cum + ns) {
            e = i;
            ls = seg - cum;
            const int left = c - ls * 64;
            rem = left < 64 ? left : 64;
        }
        cum += ns;
    }
    if (e < 0) return;                           // past the last real segment

    const int lane = threadIdx.x & 63;
    const int ent = buckets[e * REGION + ls * 64 + lane];  // row id (garbage if lane>=rem)
    const int row0 = __shfl(ent, 0, 64);         // rem >= 1 -> lane 0 valid
    const int vrow = (lane < rem) ? ent : row0;  // pad lanes dup row 0

    const int ncol  = lane & 15;        // A-row within tile / B,D column
    const int kbase = (lane >> 4) * 8;  // k offset within a K=32 step

    int arow[4];
#pragma unroll
    for (int mt = 0; mt < 4; mt++) arow[mt] = __shfl(vrow, mt * 16 + ncol, 64);

    const float* __restrict__ w1 = W1 + e * (DIM * HID);
    const float b1v = b1[e * HID + ncol];
    const float w2v = W2[e * HID + ncol];
    const float b2v = b2[e];

    const f32x4 zero = {0.0f, 0.0f, 0.0f, 0.0f};
    f32x4 acc[4] = {zero, zero, zero, zero};       // 4 M-tiles of 16 rows

#pragma unroll 1
    for (int kt = 0; kt < 4; kt++) {               // K = 128 = 4 steps of 32
        float bf[8];
        const float* wp = w1 + (kt * 32 + kbase) * HID + ncol;
#pragma unroll
        for (int t = 0; t < 8; t++) bf[t] = wp[t * HID];
        bf16x8 bh, bl;
        cvt8(bf, bh, bl);

#pragma unroll
        for (int mt = 0; mt < 4; mt++) {
            const float* xp = x + (size_t)arow[mt] * DIM + kt * 32 + kbase;
            float af[8];
            *(float4*)(af)     = *(const float4*)(xp);
            *(float4*)(af + 4) = *(const float4*)(xp + 4);
            bf16x8 ah, al;
            cvt8(af, ah, al);
            // hi*hi + lo*hi + hi*lo  (lo*lo ~2^-16 relative: dropped)
            acc[mt] = __builtin_amdgcn_mfma_f32_16x16x32_bf16(ah, bh, acc[mt], 0, 0, 0);
            acc[mt] = __builtin_amdgcn_mfma_f32_16x16x32_bf16(al, bh, acc[mt], 0, 0, 0);
            acc[mt] = __builtin_amdgcn_mfma_f32_16x16x32_bf16(ah, bl, acc[mt], 0, 0, 0);
        }
    }

    // Epilogue: D[row = mt*16 + (lane>>4)*4 + r][col = ncol] in acc[mt][r].
#pragma unroll
    for (int mt = 0; mt < 4; mt++) {
#pragma unroll
        for (int r = 0; r < 4; r++) {
            float c = fmaxf(acc[mt][r] + b1v, 0.0f) * w2v;
            c += __shfl_xor(c, 1, 64);
            c += __shfl_xor(c, 2, 64);
            c += __shfl_xor(c, 4, 64);
            c += __shfl_xor(c, 8, 64);
            const int slot = mt * 16 + (lane >> 4) * 4 + r;
            const int srow = __shfl(vrow, slot, 64);
            if (ncol == 0 && slot < rem)
                out[srow] = fmaxf(c + b2v, 0.0f);
        }
    }
}

// ---------------------------------------------------------------------------
// Fallback (only if ws_size is too small for the bucket regions).
// ---------------------------------------------------------------------------
__global__ __launch_bounds__(256) void k_naive(const float* __restrict__ x,
                                               const int* __restrict__ sid,
                                               const float* __restrict__ W1,
                                               const float* __restrict__ b1,
                                               const float* __restrict__ W2,
                                               const float* __restrict__ b2,
                                               float* __restrict__ out) {
    int row = blockIdx.x * 256 + threadIdx.x;
    if (row >= N_ROWS) return;
    int e = sid[row];
    const float* w1 = W1 + e * (DIM * HID);
    const float* xr = x + (size_t)row * DIM;
    float h[HID];
#pragma unroll
    for (int j = 0; j < HID; j++) h[j] = b1[e * HID + j];
    for (int k = 0; k < DIM; k++) {
        float xk = xr[k];
#pragma unroll
        for (int j = 0; j < HID; j++) h[j] = fmaf(xk, w1[k * HID + j], h[j]);
    }
    float acc = b2[e];
#pragma unroll
    for (int j = 0; j < HID; j++) acc = fmaf(fmaxf(h[j], 0.0f), W2[e * HID + j], acc);
    out[row] = fmaxf(acc, 0.0f);
}

extern "C" void kernel_launch(void* const* d_in, const int* in_sizes, int n_in,
                              void* d_out, int out_size, void* d_ws, size_t ws_size,
                              hipStream_t stream) {
    const float* x   = (const float*)d_in[0];
    const int*   sid = (const int*)d_in[1];
    const float* W1  = (const float*)d_in[2];
    const float* b1  = (const float*)d_in[3];
    const float* W2  = (const float*)d_in[4];
    const float* b2  = (const float*)d_in[5];
    float* out = (float*)d_out;

    // Workspace layout: buckets (NEXP fixed regions) | counts(32)
    const size_t bucketBytes = (size_t)NEXP * REGION * sizeof(int);   // ~22 MB
    const size_t countBytes  = 32 * sizeof(int);
    const size_t need = bucketBytes + countBytes;

    if (ws_size < need) {
        k_naive<<<(N_ROWS + 255) / 256, 256, 0, stream>>>(x, sid, W1, b1, W2, b2, out);
        return;
    }

    char* ws = (char*)d_ws;
    int* buckets = (int*)ws;
    int* counts  = (int*)(ws + bucketBytes);

    hipMemsetAsync(counts, 0, countBytes, stream);              // 128 B
    k_route<<<NBLK1, 256, 0, stream>>>(sid, counts, buckets);
    k_mfma<<<(NSEG + 3) / 4, 256, 0, stream>>>(x, W1, b1, W2, b2, counts, buckets, out);
}